// Round 19
// baseline (135.458 us; speedup 1.0000x reference)
//
#include <hip/hip_runtime.h>
#include <hip/hip_bf16.h>

typedef __bf16 bf16;
typedef __bf16 bf16x4 __attribute__((ext_vector_type(4)));
typedef __bf16 bf16x8 __attribute__((ext_vector_type(8)));
typedef float  f32x4  __attribute__((ext_vector_type(4)));
typedef unsigned int u32x2 __attribute__((ext_vector_type(2)));

#define MFMA16(a, b, c) __builtin_amdgcn_mfma_f32_16x16x32_bf16((a), (b), (c), 0, 0, 0)

#define GLOBAL_AS(p) ((const __attribute__((address_space(1))) void*)(p))
#define LDS_AS(p)    ((__attribute__((address_space(3))) void*)(p))

// Problem constants
#define BATCH 4
#define TOK   1024
#define DIM   1024
#define HEADS 16
#define HD    64
#define MTOT  (BATCH * TOK)        // 4096
#define MELEM (1024u * 1024u)      // one weight matrix, elements

// ---------------------------------------------------------------------------
// Kernel 0: prep v2 — ONLY the Wo hi+lo split (X-cast and Wq/Wk/Wv casts
// are fused into k_gemmQKV's reg-staged pipeline). 512 blocks, ~16MB read.
// wsp layout (elems): [woh 1M][wol 1M]
// ---------------------------------------------------------------------------
__global__ __launch_bounds__(256) void k_prepO(
    const float* __restrict__ Wo, bf16* __restrict__ wsp)
{
    size_t i0 = ((size_t)blockIdx.x * 256 + threadIdx.x) * 8;
    f32x4 a = *(const f32x4*)(Wo + i0);
    f32x4 b = *(const f32x4*)(Wo + i0 + 4);
    bf16x8 h, l;
    #pragma unroll
    for (int j = 0; j < 4; j++) {
        bf16 g0 = (bf16)a[j]; h[j] = g0;     l[j] = (bf16)(a[j] - (float)g0);
        bf16 g1 = (bf16)b[j]; h[4 + j] = g1; l[4 + j] = (bf16)(b[j] - (float)g1);
    }
    *(bf16x8*)(wsp + i0) = h;
    *(bf16x8*)(wsp + (size_t)MELEM + i0) = l;
}

// ---------------------------------------------------------------------------
// Kernel 1: fused QKV GEMM v4 — async dbuf pipeline with REG-STAGED fp32
// inputs (fuses the former cast/split prep into the GEMM's 65% stall).
// BM=128 x BN=256, 512 threads, BK=32 dbuf. T14 issue-early/write-late:
// load(k+1)->regs BEFORE compute(k); cvt + swizzled ds_write_b128 AFTER
// (all buffer reuse barrier-separated). Read-side both-sides XOR swizzle
// identical to v3 (LDS chunk c holds global chunk c ^ ((row>>1)&3)).
// N=3072 over Wq|Wk|Wv (each 256-row B-tile lies in ONE weight matrix).
// mode = nt>>2 (0:Q+RoPE*(log2e/8), 1:K+RoPE, 2:V^T).
// ---------------------------------------------------------------------------
__global__ __launch_bounds__(512) void k_gemmQKV(
    const float* __restrict__ X,
    const float* __restrict__ Wq, const float* __restrict__ Wk, const float* __restrict__ Wv,
    const float* __restrict__ cosT, const float* __restrict__ sinT,
    bf16* __restrict__ q_o, bf16* __restrict__ k_o, bf16* __restrict__ v_o)
{
    __shared__ bf16 lds[24576];        // 48KB: A0 A1 B0 B1
    bf16* A0 = lds;
    bf16* A1 = lds + 4096;
    bf16* B0 = lds + 8192;
    bf16* B1 = lds + 16384;

    const int fid = blockIdx.x;                  // 384 = 8 XCD x 48
    const int swz = (fid & 7) * 48 + (fid >> 3);
    const int nt = swz % 12;
    const int mt = swz / 12;

    const int t = threadIdx.x;
    const int lane = t & 63;
    const int w = t >> 6;
    const int wr = w >> 2, wc = w & 3;
    const int l15 = lane & 15;
    const int grp = lane >> 4;

    const int mode = nt >> 2;
    const float* Wsel = (mode == 0) ? Wq : (mode == 1) ? Wk : Wv;

    f32x4 acc[4][4];
    #pragma unroll
    for (int m = 0; m < 4; m++)
        #pragma unroll
        for (int n = 0; n < 4; n++)
            #pragma unroll
            for (int r = 0; r < 4; r++) acc[m][n][r] = 0.f;

    // A staging: thread -> (row = t>>2, 8-col group cg = t&3); 128x32 fp32
    const int arow = t >> 2, acg = t & 3;
    const float* aF = X + (size_t)(mt * 128 + arow) * DIM + acg * 8;
    const int aoff = arow * 32 + ((acg ^ ((arow >> 1) & 3)) << 3);
    // B staging: thread -> (row = t>>1, half = t&1 covering 16 cols); 256x32
    const int brow = t >> 1, bhf = t & 1;
    const float* bF = Wsel + (size_t)((nt & 3) * 256 + brow) * DIM + bhf * 16;
    const int bc0 = bhf * 2;
    const int boff0 = brow * 32 + ((bc0 ^ ((brow >> 1) & 3)) << 3);
    const int boff1 = brow * 32 + (((bc0 + 1) ^ ((brow >> 1) & 3)) << 3);

    f32x4 ra0, ra1, rb0, rb1, rb2, rb3;
    auto loadregs = [&](int k) {
        const float* ap = aF + k * 32;
        ra0 = *(const f32x4*)ap;
        ra1 = *(const f32x4*)(ap + 4);
        const float* bp = bF + k * 32;
        rb0 = *(const f32x4*)bp;
        rb1 = *(const f32x4*)(bp + 4);
        rb2 = *(const f32x4*)(bp + 8);
        rb3 = *(const f32x4*)(bp + 12);
    };
    auto cvtwrite = [&](bf16* ab, bf16* bb) {
        bf16x8 va, vb0, vb1;
        #pragma unroll
        for (int j = 0; j < 4; j++) {
            va[j] = (bf16)ra0[j];  va[4 + j] = (bf16)ra1[j];
            vb0[j] = (bf16)rb0[j]; vb0[4 + j] = (bf16)rb1[j];
            vb1[j] = (bf16)rb2[j]; vb1[4 + j] = (bf16)rb3[j];
        }
        *(bf16x8*)&ab[aoff]  = va;
        *(bf16x8*)&bb[boff0] = vb0;
        *(bf16x8*)&bb[boff1] = vb1;
    };

    auto compute = [&](const bf16* ab, const bf16* bb) {
        bf16x8 fb[4];
        #pragma unroll
        for (int n = 0; n < 4; n++) {
            int rb = wc * 64 + n * 16 + l15;
            fb[n] = *(const bf16x8*)&bb[rb * 32 + ((grp ^ ((rb >> 1) & 3)) << 3)];
        }
        __builtin_amdgcn_s_setprio(1);
        #pragma unroll
        for (int m = 0; m < 4; m++) {
            int r = wr * 64 + m * 16 + l15;
            bf16x8 fa = *(const bf16x8*)&ab[r * 32 + ((grp ^ ((r >> 1) & 3)) << 3)];
            #pragma unroll
            for (int n = 0; n < 4; n++)
                acc[m][n] = MFMA16(fa, fb[n], acc[m][n]);
        }
        __builtin_amdgcn_s_setprio(0);
    };

    loadregs(0);
    cvtwrite(A0, B0);
    __syncthreads();
    #pragma unroll 1
    for (int kk = 0; kk < 16; kk++) {
        loadregs(2 * kk + 1);            // in flight over compute
        compute(A0, B0);                 // tile 2kk
        cvtwrite(A1, B1);                // tile 2kk+1 (prior readers barrier-sep)
        __syncthreads();
        if (kk < 15) loadregs(2 * kk + 2);
        compute(A1, B1);                 // tile 2kk+1
        if (kk < 15) cvtwrite(A0, B0);   // tile 2kk+2
        __syncthreads();
    }

    const int h = (nt & 3) * 4 + wc;
    if (mode == 2) {
        #pragma unroll
        for (int m = 0; m < 4; m++) {
            const int grow0 = mt * 128 + wr * 64 + m * 16 + grp * 4;
            const int b = grow0 >> 10, ntok0 = grow0 & (TOK - 1);
            #pragma unroll
            for (int n = 0; n < 4; n++) {
                const int d = n * 16 + l15;
                bf16x4 pk;
                #pragma unroll
                for (int r = 0; r < 4; r++) pk[r] = (bf16)acc[m][n][r];
                *(bf16x4*)&v_o[((size_t)((b * HEADS + h) * HD + d)) * TOK + ntok0] = pk;
            }
        }
    } else {
        __syncthreads();
        float* cosL = (float*)lds;
        float* sinL = (float*)(lds + 8192);
        const int tb = (mt & 7) * 128;
        *(f32x4*)(cosL + t * 8)     = *(const f32x4*)(cosT + (size_t)tb * 32 + t * 8);
        *(f32x4*)(cosL + t * 8 + 4) = *(const f32x4*)(cosT + (size_t)tb * 32 + t * 8 + 4);
        *(f32x4*)(sinL + t * 8)     = *(const f32x4*)(sinT + (size_t)tb * 32 + t * 8);
        *(f32x4*)(sinL + t * 8 + 4) = *(const f32x4*)(sinT + (size_t)tb * 32 + t * 8 + 4);
        __syncthreads();

        bf16* dst = (mode == 0) ? q_o : k_o;
        const float sc = (mode == 0) ? 0.18033688f : 1.0f;   // (1/8)*log2(e) on Q
        #pragma unroll
        for (int m = 0; m < 4; m++) {
            const int grow0 = mt * 128 + wr * 64 + m * 16 + grp * 4;
            const int b = grow0 >> 10, ntok0 = grow0 & (TOK - 1);
            const int loc0 = wr * 64 + m * 16 + grp * 4;
            #pragma unroll
            for (int n = 0; n < 4; n++) {
                const int d = n * 16 + l15;
                const int idp = (d >> 5) * 16 + ((d >> 1) & 15);
                const bool ev = (d & 1) == 0;
                #pragma unroll
                for (int r = 0; r < 4; r++) {
                    float v = acc[m][n][r];
                    float pr = __shfl_xor(v, 1, 64);
                    float c = cosL[(loc0 + r) * 32 + idp];
                    float s = sinL[(loc0 + r) * 32 + idp];
                    float res = (ev ? (c * v - s * pr) : (s * pr + c * v)) * sc;
                    dst[((size_t)(b * HEADS + h) * TOK + ntok0 + r) * HD + d] = (bf16)res;
                }
            }
        }
    }
}

// ---------------------------------------------------------------------------
// Kernel 3: out-projection v2 (verified R13-R18). BM=64 x BN=128,
// grid 512 = 2 blocks/CU. 2-term split Wo from wsp [woh 1M][wol 1M].
// ---------------------------------------------------------------------------
__global__ __launch_bounds__(256) void k_gemmO(
    const bf16* __restrict__ Ag, const bf16* __restrict__ wsp,
    const float* __restrict__ bo, float* __restrict__ f_o)
{
    __shared__ bf16 Alin[64 * 64];     // 8KB
    __shared__ bf16 Bhlin[128 * 64];   // 16KB
    __shared__ bf16 Bllin[128 * 64];   // 16KB

    const bf16* Bh_g = wsp;
    const bf16* Bl_g = wsp + (size_t)MELEM;

    const int fid = blockIdx.x;
    const int swz = (fid & 7) * 64 + (fid >> 3);
    const int nt = swz & 7;
    const int mt = swz >> 3;

    const int t = threadIdx.x;
    const int lane = t & 63;
    const int w = t >> 6;
    const int wr = w >> 1, wc = w & 1;
    const int l15 = lane & 15;

    f32x4 acc[2][4];
    #pragma unroll
    for (int m = 0; m < 2; m++)
        #pragma unroll
        for (int n = 0; n < 4; n++)
            #pragma unroll
            for (int r = 0; r < 4; r++) acc[m][n][r] = 0.f;

    const int srow = lane >> 3;
    const int schk8 = ((lane & 7) ^ (srow & 7)) * 8;
    const bf16* asrc  = Ag   + (size_t)(mt * 64 + srow) * DIM + schk8;
    const bf16* bhsrc = Bh_g + (size_t)(nt * 128 + srow) * DIM + schk8;
    const bf16* blsrc = Bl_g + (size_t)(nt * 128 + srow) * DIM + schk8;

    for (int k0 = 0; k0 < DIM; k0 += 64) {
        __syncthreads();
        #pragma unroll
        for (int ii = 0; ii < 2; ++ii) {
            int i = w * 2 + ii;
            __builtin_amdgcn_global_load_lds(
                GLOBAL_AS(asrc + (size_t)i * 8 * DIM + k0),
                LDS_AS(&Alin[i * 512]), 16, 0, 0);
        }
        #pragma unroll
        for (int jj = 0; jj < 4; ++jj) {
            int j = w * 4 + jj;
            size_t roff = (size_t)j * 8 * DIM + k0;
            __builtin_amdgcn_global_load_lds(GLOBAL_AS(bhsrc + roff),
                                             LDS_AS(&Bhlin[j * 512]), 16, 0, 0);
            __builtin_amdgcn_global_load_lds(GLOBAL_AS(blsrc + roff),
                                             LDS_AS(&Bllin[j * 512]), 16, 0, 0);
        }
        __syncthreads();

        #pragma unroll
        for (int ks = 0; ks < 2; ks++) {
            const int cc = (lane >> 4) + ks * 4;
            bf16x8 fbh[4], fbl[4];
            #pragma unroll
            for (int n = 0; n < 4; n++) {
                int r = wc * 64 + n * 16 + l15;
                int off = r * 64 + ((cc ^ (r & 7)) << 3);
                fbh[n] = *(const bf16x8*)&Bhlin[off];
                fbl[n] = *(const bf16x8*)&Bllin[off];
            }
            #pragma unroll
            for (int m = 0; m < 2; m++) {
                int r = wr * 32 + m * 16 + l15;
                bf16x8 fa = *(const bf16x8*)&Alin[r * 64 + ((cc ^ (r & 7)) << 3)];
                #pragma unroll
                for (int n = 0; n < 4; n++) {
                    acc[m][n] = MFMA16(fa, fbh[n], acc[m][n]);
                    acc[m][n] = MFMA16(fa, fbl[n], acc[m][n]);
                }
            }
        }
    }

    #pragma unroll
    for (int m = 0; m < 2; m++) {
        #pragma unroll
        for (int n = 0; n < 4; n++) {
            const int grow0 = mt * 64 + wr * 32 + m * 16 + (lane >> 4) * 4;
            const int gcol  = nt * 128 + wc * 64 + n * 16 + l15;
            const float bias = bo[gcol];
            #pragma unroll
            for (int r = 0; r < 4; r++)
                f_o[(size_t)(grow0 + r) * DIM + gcol] = acc[m][n][r] + bias;
        }
    }
}

// ---------------------------------------------------------------------------
// Kernel 2: flash attention v9 (verified R18) — async dbuf + T15 att[2]
// double-pipeline. 64q/block, 4 blocks/CU, setprio, exp2 raw, l on MFMA.
// ---------------------------------------------------------------------------
__global__ __launch_bounds__(256) void k_attn(
    const bf16* __restrict__ Q, const bf16* __restrict__ K,
    const bf16* __restrict__ Vt, bf16* __restrict__ O)
{
    __shared__ bf16 Ks0[64 * 64];
    __shared__ bf16 Ks1[64 * 64];
    __shared__ bf16 Vs0[64 * 64];
    __shared__ bf16 Vs1[64 * 64];
    __shared__ bf16 Ps[64 * 64];

    const int fid = blockIdx.x;
    const int swz = (fid & 7) * 128 + (fid >> 3);
    const int qt = swz & 15;
    const int bh = swz >> 4;

    const int t = threadIdx.x;
    const int lane = t & 63;
    const int w = t >> 6;
    const int col = lane & 15;
    const int grp = lane >> 4;
    const int m7 = col & 7;
    const int qrow = w * 16 + col;

    const bf16* qp = Q + ((size_t)bh * TOK + qt * 64 + qrow) * HD + grp * 8;
    bf16x8 qf0 = *(const bf16x8*)qp;
    bf16x8 qf1 = *(const bf16x8*)(qp + 32);

    const int srow = lane >> 3;
    const int schk8 = ((lane & 7) ^ (srow & 7)) * 8;
    const bf16* ksrc = K  + ((size_t)bh * TOK + srow) * HD + schk8;
    const bf16* vsrc = Vt + ((size_t)bh * HD + srow) * TOK + schk8;

    bf16x8 ones;
    #pragma unroll
    for (int j = 0; j < 8; j++) ones[j] = (bf16)1.0f;

    f32x4 zero = {0.f, 0.f, 0.f, 0.f};
    f32x4 lacc = zero;
    f32x4 o_[4];
    #pragma unroll
    for (int dt = 0; dt < 4; dt++) o_[dt] = zero;

    unsigned int* PsU = (unsigned int*)Ps;

    auto stageK = [&](int kt, bf16* kb) {
        #pragma unroll
        for (int ii = 0; ii < 2; ++ii) {
            int i = w * 2 + ii;
            __builtin_amdgcn_global_load_lds(
                GLOBAL_AS(ksrc + (size_t)(kt * 64 + i * 8) * HD),
                LDS_AS(kb + i * 512), 16, 0, 0);
        }
    };
    auto stageV = [&](int kt, bf16* vb) {
        #pragma unroll
        for (int ii = 0; ii < 2; ++ii) {
            int i = w * 2 + ii;
            __builtin_amdgcn_global_load_lds(
                GLOBAL_AS(vsrc + (size_t)(i * 8) * TOK + kt * 64),
                LDS_AS(vb + i * 512), 16, 0, 0);
        }
    };

    auto qkt = [&](const bf16* kb, f32x4* s) {
        #pragma unroll
        for (int ct = 0; ct < 4; ct++) s[ct] = zero;
        __builtin_amdgcn_s_setprio(1);
        #pragma unroll
        for (int ct = 0; ct < 4; ct++) {
            int rbase = (ct * 16 + col) * 64;
            bf16x8 kf0 = *(const bf16x8*)&kb[rbase + ((grp ^ m7) << 3)];
            bf16x8 kf1 = *(const bf16x8*)&kb[rbase + (((grp + 4) ^ m7) << 3)];
            s[ct] = MFMA16(kf0, qf0, s[ct]);
            s[ct] = MFMA16(kf1, qf1, s[ct]);
        }
        __builtin_amdgcn_s_setprio(0);
    };

    auto packpv = [&](const f32x4* s, const bf16* vb) {
        #pragma unroll
        for (int ct = 0; ct < 4; ct++) {
            float p0 = exp2f(s[ct][0]);
            float p1 = exp2f(s[ct][1]);
            float p2 = exp2f(s[ct][2]);
            float p3 = exp2f(s[ct][3]);
            unsigned int a0, a1;
            asm("v_cvt_pk_bf16_f32 %0, %1, %2" : "=v"(a0) : "v"(p0), "v"(p1));
            asm("v_cvt_pk_bf16_f32 %0, %1, %2" : "=v"(a1) : "v"(p2), "v"(p3));
            int cs = (2 * ct + (grp >> 1)) ^ m7;
            u32x2 st = {a0, a1};
            *(u32x2*)&PsU[qrow * 32 + cs * 4 + (grp & 1) * 2] = st;
        }
        __builtin_amdgcn_s_setprio(1);
        #pragma unroll
        for (int tt = 0; tt < 2; tt++) {
            const int coff = ((4 * tt + grp) ^ m7) << 3;
            bf16x8 pf = *(const bf16x8*)&Ps[qrow * 64 + coff];
            lacc = MFMA16(ones, pf, lacc);
            #pragma unroll
            for (int dt = 0; dt < 4; dt++) {
                bf16x8 vf = *(const bf16x8*)&vb[(dt * 16 + col) * 64 + coff];
                o_[dt] = MFMA16(vf, pf, o_[dt]);
            }
        }
        __builtin_amdgcn_s_setprio(0);
    };

    f32x4 sa[4], sprev[4];

    stageK(0, Ks0);
    stageV(0, Vs0);
    #pragma unroll 1
    for (int kk = 0; kk < 8; kk++) {
        __syncthreads();
        stageK(2 * kk + 1, Ks1);
        if (kk > 0) stageV(2 * kk, Vs0);
        qkt(Ks0, sa);
        if (kk > 0) packpv(sprev, Vs1);
        __syncthreads();
        if (kk < 7) stageK(2 * kk + 2, Ks0);
        stageV(2 * kk + 1, Vs1);
        qkt(Ks1, sprev);
        packpv(sa, Vs0);
    }
    __syncthreads();
    packpv(sprev, Vs1);

    const float inv = 1.0f / lacc[0];

    const int b = bh >> 4, h = bh & 15;
    const int ntok = qt * 64 + qrow;
    #pragma unroll
    for (int dt = 0; dt < 4; dt++) {
        bf16x4 pk4;
        #pragma unroll
        for (int r = 0; r < 4; r++) pk4[r] = (bf16)(o_[dt][r] * inv);
        *(bf16x4*)&O[((size_t)b * TOK + ntok) * DIM + h * HD + dt * 16 + grp * 4] = pk4;
    }
}

// ---------------------------------------------------------------------------
extern "C" void kernel_launch(void* const* d_in, const int* in_sizes, int n_in,
                              void* d_out, int out_size, void* d_ws, size_t ws_size,
                              hipStream_t stream)
{
    const float* x    = (const float*)d_in[0];
    const float* cosT = (const float*)d_in[1];
    const float* sinT = (const float*)d_in[2];
    const float* Wq   = (const float*)d_in[3];
    const float* Wk   = (const float*)d_in[4];
    const float* Wv   = (const float*)d_in[5];
    const float* Wo   = (const float*)d_in[6];
    const float* bo   = (const float*)d_in[7];
    float* out = (float*)d_out;

    // ws layout (bf16 elems): ow[0,4M) qw[4M,8M) kw[8M,12M) vw[12M,16M)
    // wsp[16M,18M) = [woh|wol] (36MB total used).
    bf16* ow  = (bf16*)d_ws;
    bf16* qw  = ow + 4 * (size_t)MELEM;
    bf16* kw  = qw + 4 * (size_t)MELEM;
    bf16* vw  = kw + 4 * (size_t)MELEM;
    bf16* wsp = vw + 4 * (size_t)MELEM;

    k_prepO<<<dim3(512), dim3(256), 0, stream>>>(Wo, wsp);
    k_gemmQKV<<<dim3(384), dim3(512), 0, stream>>>(x, Wq, Wk, Wv, cosT, sinT, qw, kw, vw);
    k_attn<<<dim3(1024), dim3(256), 0, stream>>>(qw, kw, vw, ow);
    k_gemmO<<<dim3(512), dim3(256), 0, stream>>>(ow, wsp, bo, out);
}

// Round 20
// 98.938 us; speedup vs baseline: 1.3691x; 1.3691x over previous
//
#include <hip/hip_runtime.h>
#include <hip/hip_bf16.h>

typedef __bf16 bf16;
typedef __bf16 bf16x4 __attribute__((ext_vector_type(4)));
typedef __bf16 bf16x8 __attribute__((ext_vector_type(8)));
typedef float  f32x4  __attribute__((ext_vector_type(4)));
typedef unsigned int u32x2 __attribute__((ext_vector_type(2)));

#define MFMA16(a, b, c) __builtin_amdgcn_mfma_f32_16x16x32_bf16((a), (b), (c), 0, 0, 0)

#define GLOBAL_AS(p) ((const __attribute__((address_space(1))) void*)(p))
#define LDS_AS(p)    ((__attribute__((address_space(3))) void*)(p))

// Problem constants
#define BATCH 4
#define TOK   1024
#define DIM   1024
#define HEADS 16
#define HD    64
#define MTOT  (BATCH * TOK)        // 4096
#define MELEM (1024u * 1024u)      // one weight matrix, elements

// ---------------------------------------------------------------------------
// Kernel 0: fused prep (verified R9-R18). cast X; split weights.
// wsp layout (elems): [wqh 1M][wkh 1M][wvh 1M][woh 1M][wol 1M]
// ---------------------------------------------------------------------------
__global__ __launch_bounds__(256) void k_prep(
    const float* __restrict__ X,
    const float* __restrict__ W0, const float* __restrict__ W1,
    const float* __restrict__ W2, const float* __restrict__ W3,
    bf16* __restrict__ xh, bf16* __restrict__ wsp)
{
    const int bid = blockIdx.x;
    if (bid < 2048) {
        size_t i0 = ((size_t)bid * 256 + threadIdx.x) * 8;
        f32x4 a = *(const f32x4*)(X + i0);
        f32x4 b = *(const f32x4*)(X + i0 + 4);
        bf16x8 h;
        #pragma unroll
        for (int j = 0; j < 4; j++) { h[j] = (bf16)a[j]; h[4 + j] = (bf16)b[j]; }
        *(bf16x8*)(xh + i0) = h;
    } else {
        const int b2 = bid - 2048;
        const int widx = b2 >> 9;
        const int inner = b2 & 511;
        const float* W = (widx == 0) ? W0 : (widx == 1) ? W1 : (widx == 2) ? W2 : W3;
        size_t i0 = ((size_t)inner * 256 + threadIdx.x) * 8;
        f32x4 a = *(const f32x4*)(W + i0);
        f32x4 b = *(const f32x4*)(W + i0 + 4);
        bf16x8 h, l;
        #pragma unroll
        for (int j = 0; j < 4; j++) {
            bf16 g0 = (bf16)a[j]; h[j] = g0;     l[j] = (bf16)(a[j] - (float)g0);
            bf16 g1 = (bf16)b[j]; h[4 + j] = g1; l[4 + j] = (bf16)(b[j] - (float)g1);
        }
        *(bf16x8*)(wsp + (size_t)widx * MELEM + i0) = h;
        if (widx == 3)
            *(bf16x8*)(wsp + 4 * (size_t)MELEM + i0) = l;   // Wo lo term
    }
}

// ---------------------------------------------------------------------------
// Kernel 1: fused QKV GEMM v3 (verified R15-R18) — async dbuf pipeline,
// BM=128 x BN=256, 512 threads, BK=32 dbuf, both-sides XOR swizzle.
// N=3072 over [wqh|wkh|wvh]; mode = nt>>2. Q scale folds (1/8)*log2(e).
// ---------------------------------------------------------------------------
__global__ __launch_bounds__(512) void k_gemmQKV(
    const bf16* __restrict__ Ag, const bf16* __restrict__ wsp,
    const float* __restrict__ cosT, const float* __restrict__ sinT,
    bf16* __restrict__ q_o, bf16* __restrict__ k_o, bf16* __restrict__ v_o)
{
    __shared__ bf16 lds[24576];        // 48KB: A0 A1 B0 B1
    bf16* A0 = lds;
    bf16* A1 = lds + 4096;
    bf16* B0 = lds + 8192;
    bf16* B1 = lds + 16384;

    const int fid = blockIdx.x;                  // 384 = 8 XCD x 48
    const int swz = (fid & 7) * 48 + (fid >> 3);
    const int nt = swz % 12;
    const int mt = swz / 12;

    const int t = threadIdx.x;
    const int lane = t & 63;
    const int w = t >> 6;
    const int wr = w >> 2, wc = w & 3;
    const int l15 = lane & 15;
    const int grp = lane >> 4;

    f32x4 acc[4][4];
    #pragma unroll
    for (int m = 0; m < 4; m++)
        #pragma unroll
        for (int n = 0; n < 4; n++)
            #pragma unroll
            for (int r = 0; r < 4; r++) acc[m][n][r] = 0.f;

    const int srow = lane >> 2;
    const int schk8 = ((lane & 3) ^ ((lane >> 3) & 3)) * 8;
    const bf16* asrc = Ag  + (size_t)(mt * 128 + srow) * DIM + schk8;
    const bf16* bsrc = wsp + (size_t)(nt * 256 + srow) * DIM + schk8;

    auto stage = [&](int k, bf16* ab, bf16* bb) {
        const int k0 = k * 32;
        __builtin_amdgcn_global_load_lds(
            GLOBAL_AS(asrc + (size_t)w * 16 * DIM + k0),
            LDS_AS(ab + w * 512), 16, 0, 0);
        #pragma unroll
        for (int jj = 0; jj < 2; ++jj) {
            int j = w * 2 + jj;
            __builtin_amdgcn_global_load_lds(
                GLOBAL_AS(bsrc + (size_t)j * 16 * DIM + k0),
                LDS_AS(bb + j * 512), 16, 0, 0);
        }
    };

    auto compute = [&](const bf16* ab, const bf16* bb) {
        bf16x8 fb[4];
        #pragma unroll
        for (int n = 0; n < 4; n++) {
            int rb = wc * 64 + n * 16 + l15;
            fb[n] = *(const bf16x8*)&bb[rb * 32 + ((grp ^ ((rb >> 1) & 3)) << 3)];
        }
        __builtin_amdgcn_s_setprio(1);
        #pragma unroll
        for (int m = 0; m < 4; m++) {
            int r = wr * 64 + m * 16 + l15;
            bf16x8 fa = *(const bf16x8*)&ab[r * 32 + ((grp ^ ((r >> 1) & 3)) << 3)];
            #pragma unroll
            for (int n = 0; n < 4; n++)
                acc[m][n] = MFMA16(fa, fb[n], acc[m][n]);
        }
        __builtin_amdgcn_s_setprio(0);
    };

    stage(0, A0, B0);
    #pragma unroll 1
    for (int kk = 0; kk < 16; kk++) {
        __syncthreads();
        stage(2 * kk + 1, A1, B1);
        compute(A0, B0);
        __syncthreads();
        if (kk < 15) stage(2 * kk + 2, A0, B0);
        compute(A1, B1);
    }

    const int mode = nt >> 2;
    const int h = (nt & 3) * 4 + wc;
    if (mode == 2) {
        #pragma unroll
        for (int m = 0; m < 4; m++) {
            const int grow0 = mt * 128 + wr * 64 + m * 16 + grp * 4;
            const int b = grow0 >> 10, ntok0 = grow0 & (TOK - 1);
            #pragma unroll
            for (int n = 0; n < 4; n++) {
                const int d = n * 16 + l15;
                bf16x4 pk;
                #pragma unroll
                for (int r = 0; r < 4; r++) pk[r] = (bf16)acc[m][n][r];
                *(bf16x4*)&v_o[((size_t)((b * HEADS + h) * HD + d)) * TOK + ntok0] = pk;
            }
        }
    } else {
        __syncthreads();
        float* cosL = (float*)lds;
        float* sinL = (float*)(lds + 8192);
        const int tb = (mt & 7) * 128;
        *(f32x4*)(cosL + t * 8)     = *(const f32x4*)(cosT + (size_t)tb * 32 + t * 8);
        *(f32x4*)(cosL + t * 8 + 4) = *(const f32x4*)(cosT + (size_t)tb * 32 + t * 8 + 4);
        *(f32x4*)(sinL + t * 8)     = *(const f32x4*)(sinT + (size_t)tb * 32 + t * 8);
        *(f32x4*)(sinL + t * 8 + 4) = *(const f32x4*)(sinT + (size_t)tb * 32 + t * 8 + 4);
        __syncthreads();

        bf16* dst = (mode == 0) ? q_o : k_o;
        const float sc = (mode == 0) ? 0.18033688f : 1.0f;   // (1/8)*log2(e) on Q
        #pragma unroll
        for (int m = 0; m < 4; m++) {
            const int grow0 = mt * 128 + wr * 64 + m * 16 + grp * 4;
            const int b = grow0 >> 10, ntok0 = grow0 & (TOK - 1);
            const int loc0 = wr * 64 + m * 16 + grp * 4;
            #pragma unroll
            for (int n = 0; n < 4; n++) {
                const int d = n * 16 + l15;
                const int idp = (d >> 5) * 16 + ((d >> 1) & 15);
                const bool ev = (d & 1) == 0;
                #pragma unroll
                for (int r = 0; r < 4; r++) {
                    float v = acc[m][n][r];
                    float pr = __shfl_xor(v, 1, 64);
                    float c = cosL[(loc0 + r) * 32 + idp];
                    float s = sinL[(loc0 + r) * 32 + idp];
                    float res = (ev ? (c * v - s * pr) : (s * pr + c * v)) * sc;
                    dst[((size_t)(b * HEADS + h) * TOK + ntok0 + r) * HD + d] = (bf16)res;
                }
            }
        }
    }
}

// ---------------------------------------------------------------------------
// Kernel 3: out-projection v2 (verified R13-R18). BM=64 x BN=128,
// grid 512 = 2 blocks/CU. 2-term split Wo.
// ---------------------------------------------------------------------------
__global__ __launch_bounds__(256) void k_gemmO(
    const bf16* __restrict__ Ag, const bf16* __restrict__ wsp,
    const float* __restrict__ bo, float* __restrict__ f_o)
{
    __shared__ bf16 Alin[64 * 64];     // 8KB
    __shared__ bf16 Bhlin[128 * 64];   // 16KB
    __shared__ bf16 Bllin[128 * 64];   // 16KB

    const bf16* Bh_g = wsp + 3 * (size_t)MELEM;
    const bf16* Bl_g = wsp + 4 * (size_t)MELEM;

    const int fid = blockIdx.x;
    const int swz = (fid & 7) * 64 + (fid >> 3);
    const int nt = swz & 7;
    const int mt = swz >> 3;

    const int t = threadIdx.x;
    const int lane = t & 63;
    const int w = t >> 6;
    const int wr = w >> 1, wc = w & 1;
    const int l15 = lane & 15;

    f32x4 acc[2][4];
    #pragma unroll
    for (int m = 0; m < 2; m++)
        #pragma unroll
        for (int n = 0; n < 4; n++)
            #pragma unroll
            for (int r = 0; r < 4; r++) acc[m][n][r] = 0.f;

    const int srow = lane >> 3;
    const int schk8 = ((lane & 7) ^ (srow & 7)) * 8;
    const bf16* asrc  = Ag   + (size_t)(mt * 64 + srow) * DIM + schk8;
    const bf16* bhsrc = Bh_g + (size_t)(nt * 128 + srow) * DIM + schk8;
    const bf16* blsrc = Bl_g + (size_t)(nt * 128 + srow) * DIM + schk8;

    for (int k0 = 0; k0 < DIM; k0 += 64) {
        __syncthreads();
        #pragma unroll
        for (int ii = 0; ii < 2; ++ii) {
            int i = w * 2 + ii;
            __builtin_amdgcn_global_load_lds(
                GLOBAL_AS(asrc + (size_t)i * 8 * DIM + k0),
                LDS_AS(&Alin[i * 512]), 16, 0, 0);
        }
        #pragma unroll
        for (int jj = 0; jj < 4; ++jj) {
            int j = w * 4 + jj;
            size_t roff = (size_t)j * 8 * DIM + k0;
            __builtin_amdgcn_global_load_lds(GLOBAL_AS(bhsrc + roff),
                                             LDS_AS(&Bhlin[j * 512]), 16, 0, 0);
            __builtin_amdgcn_global_load_lds(GLOBAL_AS(blsrc + roff),
                                             LDS_AS(&Bllin[j * 512]), 16, 0, 0);
        }
        __syncthreads();

        #pragma unroll
        for (int ks = 0; ks < 2; ks++) {
            const int cc = (lane >> 4) + ks * 4;
            bf16x8 fbh[4], fbl[4];
            #pragma unroll
            for (int n = 0; n < 4; n++) {
                int r = wc * 64 + n * 16 + l15;
                int off = r * 64 + ((cc ^ (r & 7)) << 3);
                fbh[n] = *(const bf16x8*)&Bhlin[off];
                fbl[n] = *(const bf16x8*)&Bllin[off];
            }
            #pragma unroll
            for (int m = 0; m < 2; m++) {
                int r = wr * 32 + m * 16 + l15;
                bf16x8 fa = *(const bf16x8*)&Alin[r * 64 + ((cc ^ (r & 7)) << 3)];
                #pragma unroll
                for (int n = 0; n < 4; n++) {
                    acc[m][n] = MFMA16(fa, fbh[n], acc[m][n]);
                    acc[m][n] = MFMA16(fa, fbl[n], acc[m][n]);
                }
            }
        }
    }

    #pragma unroll
    for (int m = 0; m < 2; m++) {
        #pragma unroll
        for (int n = 0; n < 4; n++) {
            const int grow0 = mt * 64 + wr * 32 + m * 16 + (lane >> 4) * 4;
            const int gcol  = nt * 128 + wc * 64 + n * 16 + l15;
            const float bias = bo[gcol];
            #pragma unroll
            for (int r = 0; r < 4; r++)
                f_o[(size_t)(grow0 + r) * DIM + gcol] = acc[m][n][r] + bias;
        }
    }
}

// ---------------------------------------------------------------------------
// Kernel 2: flash attention v9 (verified R18) — async dbuf + T15 att[2]
// double-pipeline. 64q/block, 4 blocks/CU, setprio, exp2 raw, l on MFMA.
// ---------------------------------------------------------------------------
__global__ __launch_bounds__(256) void k_attn(
    const bf16* __restrict__ Q, const bf16* __restrict__ K,
    const bf16* __restrict__ Vt, bf16* __restrict__ O)
{
    __shared__ bf16 Ks0[64 * 64];
    __shared__ bf16 Ks1[64 * 64];
    __shared__ bf16 Vs0[64 * 64];
    __shared__ bf16 Vs1[64 * 64];
    __shared__ bf16 Ps[64 * 64];

    const int fid = blockIdx.x;
    const int swz = (fid & 7) * 128 + (fid >> 3);
    const int qt = swz & 15;
    const int bh = swz >> 4;

    const int t = threadIdx.x;
    const int lane = t & 63;
    const int w = t >> 6;
    const int col = lane & 15;
    const int grp = lane >> 4;
    const int m7 = col & 7;
    const int qrow = w * 16 + col;

    const bf16* qp = Q + ((size_t)bh * TOK + qt * 64 + qrow) * HD + grp * 8;
    bf16x8 qf0 = *(const bf16x8*)qp;
    bf16x8 qf1 = *(const bf16x8*)(qp + 32);

    const int srow = lane >> 3;
    const int schk8 = ((lane & 7) ^ (srow & 7)) * 8;
    const bf16* ksrc = K  + ((size_t)bh * TOK + srow) * HD + schk8;
    const bf16* vsrc = Vt + ((size_t)bh * HD + srow) * TOK + schk8;

    bf16x8 ones;
    #pragma unroll
    for (int j = 0; j < 8; j++) ones[j] = (bf16)1.0f;

    f32x4 zero = {0.f, 0.f, 0.f, 0.f};
    f32x4 lacc = zero;
    f32x4 o_[4];
    #pragma unroll
    for (int dt = 0; dt < 4; dt++) o_[dt] = zero;

    unsigned int* PsU = (unsigned int*)Ps;

    auto stageK = [&](int kt, bf16* kb) {
        #pragma unroll
        for (int ii = 0; ii < 2; ++ii) {
            int i = w * 2 + ii;
            __builtin_amdgcn_global_load_lds(
                GLOBAL_AS(ksrc + (size_t)(kt * 64 + i * 8) * HD),
                LDS_AS(kb + i * 512), 16, 0, 0);
        }
    };
    auto stageV = [&](int kt, bf16* vb) {
        #pragma unroll
        for (int ii = 0; ii < 2; ++ii) {
            int i = w * 2 + ii;
            __builtin_amdgcn_global_load_lds(
                GLOBAL_AS(vsrc + (size_t)(i * 8) * TOK + kt * 64),
                LDS_AS(vb + i * 512), 16, 0, 0);
        }
    };

    auto qkt = [&](const bf16* kb, f32x4* s) {
        #pragma unroll
        for (int ct = 0; ct < 4; ct++) s[ct] = zero;
        __builtin_amdgcn_s_setprio(1);
        #pragma unroll
        for (int ct = 0; ct < 4; ct++) {
            int rbase = (ct * 16 + col) * 64;
            bf16x8 kf0 = *(const bf16x8*)&kb[rbase + ((grp ^ m7) << 3)];
            bf16x8 kf1 = *(const bf16x8*)&kb[rbase + (((grp + 4) ^ m7) << 3)];
            s[ct] = MFMA16(kf0, qf0, s[ct]);
            s[ct] = MFMA16(kf1, qf1, s[ct]);
        }
        __builtin_amdgcn_s_setprio(0);
    };

    auto packpv = [&](const f32x4* s, const bf16* vb) {
        #pragma unroll
        for (int ct = 0; ct < 4; ct++) {
            float p0 = exp2f(s[ct][0]);
            float p1 = exp2f(s[ct][1]);
            float p2 = exp2f(s[ct][2]);
            float p3 = exp2f(s[ct][3]);
            unsigned int a0, a1;
            asm("v_cvt_pk_bf16_f32 %0, %1, %2" : "=v"(a0) : "v"(p0), "v"(p1));
            asm("v_cvt_pk_bf16_f32 %0, %1, %2" : "=v"(a1) : "v"(p2), "v"(p3));
            int cs = (2 * ct + (grp >> 1)) ^ m7;
            u32x2 st = {a0, a1};
            *(u32x2*)&PsU[qrow * 32 + cs * 4 + (grp & 1) * 2] = st;
        }
        __builtin_amdgcn_s_setprio(1);
        #pragma unroll
        for (int tt = 0; tt < 2; tt++) {
            const int coff = ((4 * tt + grp) ^ m7) << 3;
            bf16x8 pf = *(const bf16x8*)&Ps[qrow * 64 + coff];
            lacc = MFMA16(ones, pf, lacc);
            #pragma unroll
            for (int dt = 0; dt < 4; dt++) {
                bf16x8 vf = *(const bf16x8*)&vb[(dt * 16 + col) * 64 + coff];
                o_[dt] = MFMA16(vf, pf, o_[dt]);
            }
        }
        __builtin_amdgcn_s_setprio(0);
    };

    f32x4 sa[4], sprev[4];

    stageK(0, Ks0);
    stageV(0, Vs0);
    #pragma unroll 1
    for (int kk = 0; kk < 8; kk++) {
        __syncthreads();
        stageK(2 * kk + 1, Ks1);
        if (kk > 0) stageV(2 * kk, Vs0);
        qkt(Ks0, sa);
        if (kk > 0) packpv(sprev, Vs1);
        __syncthreads();
        if (kk < 7) stageK(2 * kk + 2, Ks0);
        stageV(2 * kk + 1, Vs1);
        qkt(Ks1, sprev);
        packpv(sa, Vs0);
    }
    __syncthreads();
    packpv(sprev, Vs1);

    const float inv = 1.0f / lacc[0];

    const int b = bh >> 4, h = bh & 15;
    const int ntok = qt * 64 + qrow;
    #pragma unroll
    for (int dt = 0; dt < 4; dt++) {
        bf16x4 pk4;
        #pragma unroll
        for (int r = 0; r < 4; r++) pk4[r] = (bf16)(o_[dt][r] * inv);
        *(bf16x4*)&O[((size_t)b * TOK + ntok) * DIM + h * HD + dt * 16 + grp * 4] = pk4;
    }
}

// ---------------------------------------------------------------------------
extern "C" void kernel_launch(void* const* d_in, const int* in_sizes, int n_in,
                              void* d_out, int out_size, void* d_ws, size_t ws_size,
                              hipStream_t stream)
{
    const float* x    = (const float*)d_in[0];
    const float* cosT = (const float*)d_in[1];
    const float* sinT = (const float*)d_in[2];
    const float* Wq   = (const float*)d_in[3];
    const float* Wk   = (const float*)d_in[4];
    const float* Wv   = (const float*)d_in[5];
    const float* Wo   = (const float*)d_in[6];
    const float* bo   = (const float*)d_in[7];
    float* out = (float*)d_out;

    // ws layout (bf16 elems): xh[0,4M) qw[4M,8M) kw[8M,12M) vw[12M,16M)
    // wsp[16M,21M) = 42MB. ow aliases xh (xh dead after QKV GEMM).
    bf16* xh  = (bf16*)d_ws;
    bf16* qw  = xh + 4 * (size_t)MELEM;
    bf16* kw  = qw + 4 * (size_t)MELEM;
    bf16* vw  = kw + 4 * (size_t)MELEM;
    bf16* wsp = vw + 4 * (size_t)MELEM;
    bf16* ow  = xh;

    k_prep<<<dim3(4096), dim3(256), 0, stream>>>(x, Wq, Wk, Wv, Wo, xh, wsp);
    k_gemmQKV<<<dim3(384), dim3(512), 0, stream>>>(xh, wsp, cosT, sinT, qw, kw, vw);
    k_attn<<<dim3(1024), dim3(256), 0, stream>>>(qw, kw, vw, ow);
    k_gemmO<<<dim3(512), dim3(256), 0, stream>>>(ow, wsp, bo, out);
}

// Round 22
// 97.698 us; speedup vs baseline: 1.3865x; 1.0127x over previous
//
#include <hip/hip_runtime.h>
#include <hip/hip_bf16.h>

typedef __bf16 bf16;
typedef __bf16 bf16x4 __attribute__((ext_vector_type(4)));
typedef __bf16 bf16x8 __attribute__((ext_vector_type(8)));
typedef float  f32x4  __attribute__((ext_vector_type(4)));
typedef unsigned int u32x2 __attribute__((ext_vector_type(2)));

#define MFMA16(a, b, c) __builtin_amdgcn_mfma_f32_16x16x32_bf16((a), (b), (c), 0, 0, 0)

#define GLOBAL_AS(p) ((const __attribute__((address_space(1))) void*)(p))
#define LDS_AS(p)    ((__attribute__((address_space(3))) void*)(p))

// Problem constants
#define BATCH 4
#define TOK   1024
#define DIM   1024
#define HEADS 16
#define HD    64
#define MTOT  (BATCH * TOK)        // 4096
#define MELEM (1024u * 1024u)      // one weight matrix, elements

// ---------------------------------------------------------------------------
// Kernel 0: prep v3 — X-cast + Wq/Wk/Wv hi-splits ONLY (3584 blocks).
// The Wo hi+lo split rides inside k_gemmQKV's launch (it is only needed
// by k_gemmO, which runs after attn). wsp: [wqh 1M][wkh 1M][wvh 1M][woh][wol]
// ---------------------------------------------------------------------------
__global__ __launch_bounds__(256) void k_prep(
    const float* __restrict__ X,
    const float* __restrict__ W0, const float* __restrict__ W1,
    const float* __restrict__ W2,
    bf16* __restrict__ xh, bf16* __restrict__ wsp)
{
    const int bid = blockIdx.x;
    if (bid < 2048) {
        size_t i0 = ((size_t)bid * 256 + threadIdx.x) * 8;
        f32x4 a = *(const f32x4*)(X + i0);
        f32x4 b = *(const f32x4*)(X + i0 + 4);
        bf16x8 h;
        #pragma unroll
        for (int j = 0; j < 4; j++) { h[j] = (bf16)a[j]; h[4 + j] = (bf16)b[j]; }
        *(bf16x8*)(xh + i0) = h;
    } else {
        const int b2 = bid - 2048;
        const int widx = b2 >> 9;          // 0..2
        const int inner = b2 & 511;
        const float* W = (widx == 0) ? W0 : (widx == 1) ? W1 : W2;
        size_t i0 = ((size_t)inner * 256 + threadIdx.x) * 8;
        f32x4 a = *(const f32x4*)(W + i0);
        f32x4 b = *(const f32x4*)(W + i0 + 4);
        bf16x8 h;
        #pragma unroll
        for (int j = 0; j < 4; j++) { h[j] = (bf16)a[j]; h[4 + j] = (bf16)b[j]; }
        *(bf16x8*)(wsp + (size_t)widx * MELEM + i0) = h;
    }
}

// ---------------------------------------------------------------------------
// Kernel 1: fused QKV GEMM v3 (verified R15-R20) + piggybacked Wo split.
// Blocks [0,384): async dbuf GEMM (BM=128 x BN=256, 512 threads, BK=32
// dbuf, both-sides XOR swizzle). Blocks [384,640): Wo fp32 -> (hi,lo)
// split: 256 blocks x 512 threads x 8 elems = exactly 1M (R21's crash was
// 512 blocks here = 2x OOB). Consumed only by k_gemmO (runs after attn).
// ---------------------------------------------------------------------------
__global__ __launch_bounds__(512) void k_gemmQKV(
    const bf16* __restrict__ Ag, const bf16* __restrict__ wsp_r,
    const float* __restrict__ Wo, bf16* __restrict__ wsp_w,
    const float* __restrict__ cosT, const float* __restrict__ sinT,
    bf16* __restrict__ q_o, bf16* __restrict__ k_o, bf16* __restrict__ v_o)
{
    __shared__ bf16 lds[24576];        // 48KB: A0 A1 B0 B1
    bf16* A0 = lds;
    bf16* A1 = lds + 4096;
    bf16* B0 = lds + 8192;
    bf16* B1 = lds + 16384;

    const int fid = blockIdx.x;
    if (fid >= 384) {
        // --- piggybacked Wo split: 256 blocks x 512 threads x 8 = 1M ---
        size_t i0 = ((size_t)(fid - 384) * 512 + threadIdx.x) * 8;
        f32x4 a = *(const f32x4*)(Wo + i0);
        f32x4 b = *(const f32x4*)(Wo + i0 + 4);
        bf16x8 h, l;
        #pragma unroll
        for (int j = 0; j < 4; j++) {
            bf16 g0 = (bf16)a[j]; h[j] = g0;     l[j] = (bf16)(a[j] - (float)g0);
            bf16 g1 = (bf16)b[j]; h[4 + j] = g1; l[4 + j] = (bf16)(b[j] - (float)g1);
        }
        *(bf16x8*)(wsp_w + 3 * (size_t)MELEM + i0) = h;
        *(bf16x8*)(wsp_w + 4 * (size_t)MELEM + i0) = l;
        return;
    }

    const int swz = (fid & 7) * 48 + (fid >> 3);
    const int nt = swz % 12;
    const int mt = swz / 12;

    const int t = threadIdx.x;
    const int lane = t & 63;
    const int w = t >> 6;
    const int wr = w >> 2, wc = w & 3;
    const int l15 = lane & 15;
    const int grp = lane >> 4;

    f32x4 acc[4][4];
    #pragma unroll
    for (int m = 0; m < 4; m++)
        #pragma unroll
        for (int n = 0; n < 4; n++)
            #pragma unroll
            for (int r = 0; r < 4; r++) acc[m][n][r] = 0.f;

    const int srow = lane >> 2;
    const int schk8 = ((lane & 3) ^ ((lane >> 3) & 3)) * 8;
    const bf16* asrc = Ag    + (size_t)(mt * 128 + srow) * DIM + schk8;
    const bf16* bsrc = wsp_r + (size_t)(nt * 256 + srow) * DIM + schk8;

    auto stage = [&](int k, bf16* ab, bf16* bb) {
        const int k0 = k * 32;
        __builtin_amdgcn_global_load_lds(
            GLOBAL_AS(asrc + (size_t)w * 16 * DIM + k0),
            LDS_AS(ab + w * 512), 16, 0, 0);
        #pragma unroll
        for (int jj = 0; jj < 2; ++jj) {
            int j = w * 2 + jj;
            __builtin_amdgcn_global_load_lds(
                GLOBAL_AS(bsrc + (size_t)j * 16 * DIM + k0),
                LDS_AS(bb + j * 512), 16, 0, 0);
        }
    };

    auto compute = [&](const bf16* ab, const bf16* bb) {
        bf16x8 fb[4];
        #pragma unroll
        for (int n = 0; n < 4; n++) {
            int rb = wc * 64 + n * 16 + l15;
            fb[n] = *(const bf16x8*)&bb[rb * 32 + ((grp ^ ((rb >> 1) & 3)) << 3)];
        }
        __builtin_amdgcn_s_setprio(1);
        #pragma unroll
        for (int m = 0; m < 4; m++) {
            int r = wr * 64 + m * 16 + l15;
            bf16x8 fa = *(const bf16x8*)&ab[r * 32 + ((grp ^ ((r >> 1) & 3)) << 3)];
            #pragma unroll
            for (int n = 0; n < 4; n++)
                acc[m][n] = MFMA16(fa, fb[n], acc[m][n]);
        }
        __builtin_amdgcn_s_setprio(0);
    };

    stage(0, A0, B0);
    #pragma unroll 1
    for (int kk = 0; kk < 16; kk++) {
        __syncthreads();
        stage(2 * kk + 1, A1, B1);
        compute(A0, B0);
        __syncthreads();
        if (kk < 15) stage(2 * kk + 2, A0, B0);
        compute(A1, B1);
    }

    const int mode = nt >> 2;
    const int h = (nt & 3) * 4 + wc;
    if (mode == 2) {
        #pragma unroll
        for (int m = 0; m < 4; m++) {
            const int grow0 = mt * 128 + wr * 64 + m * 16 + grp * 4;
            const int b = grow0 >> 10, ntok0 = grow0 & (TOK - 1);
            #pragma unroll
            for (int n = 0; n < 4; n++) {
                const int d = n * 16 + l15;
                bf16x4 pk;
                #pragma unroll
                for (int r = 0; r < 4; r++) pk[r] = (bf16)acc[m][n][r];
                *(bf16x4*)&v_o[((size_t)((b * HEADS + h) * HD + d)) * TOK + ntok0] = pk;
            }
        }
    } else {
        __syncthreads();
        float* cosL = (float*)lds;
        float* sinL = (float*)(lds + 8192);
        const int tb = (mt & 7) * 128;
        *(f32x4*)(cosL + t * 8)     = *(const f32x4*)(cosT + (size_t)tb * 32 + t * 8);
        *(f32x4*)(cosL + t * 8 + 4) = *(const f32x4*)(cosT + (size_t)tb * 32 + t * 8 + 4);
        *(f32x4*)(sinL + t * 8)     = *(const f32x4*)(sinT + (size_t)tb * 32 + t * 8);
        *(f32x4*)(sinL + t * 8 + 4) = *(const f32x4*)(sinT + (size_t)tb * 32 + t * 8 + 4);
        __syncthreads();

        bf16* dst = (mode == 0) ? q_o : k_o;
        const float sc = (mode == 0) ? 0.18033688f : 1.0f;   // (1/8)*log2(e) on Q
        #pragma unroll
        for (int m = 0; m < 4; m++) {
            const int grow0 = mt * 128 + wr * 64 + m * 16 + grp * 4;
            const int b = grow0 >> 10, ntok0 = grow0 & (TOK - 1);
            const int loc0 = wr * 64 + m * 16 + grp * 4;
            #pragma unroll
            for (int n = 0; n < 4; n++) {
                const int d = n * 16 + l15;
                const int idp = (d >> 5) * 16 + ((d >> 1) & 15);
                const bool ev = (d & 1) == 0;
                #pragma unroll
                for (int r = 0; r < 4; r++) {
                    float v = acc[m][n][r];
                    float pr = __shfl_xor(v, 1, 64);
                    float c = cosL[(loc0 + r) * 32 + idp];
                    float s = sinL[(loc0 + r) * 32 + idp];
                    float res = (ev ? (c * v - s * pr) : (s * pr + c * v)) * sc;
                    dst[((size_t)(b * HEADS + h) * TOK + ntok0 + r) * HD + d] = (bf16)res;
                }
            }
        }
    }
}

// ---------------------------------------------------------------------------
// Kernel 3: out-projection v2 (verified R13-R20). BM=64 x BN=128,
// grid 512 = 2 blocks/CU. 2-term split Wo.
// ---------------------------------------------------------------------------
__global__ __launch_bounds__(256) void k_gemmO(
    const bf16* __restrict__ Ag, const bf16* __restrict__ wsp,
    const float* __restrict__ bo, float* __restrict__ f_o)
{
    __shared__ bf16 Alin[64 * 64];     // 8KB
    __shared__ bf16 Bhlin[128 * 64];   // 16KB
    __shared__ bf16 Bllin[128 * 64];   // 16KB

    const bf16* Bh_g = wsp + 3 * (size_t)MELEM;
    const bf16* Bl_g = wsp + 4 * (size_t)MELEM;

    const int fid = blockIdx.x;
    const int swz = (fid & 7) * 64 + (fid >> 3);
    const int nt = swz & 7;
    const int mt = swz >> 3;

    const int t = threadIdx.x;
    const int lane = t & 63;
    const int w = t >> 6;
    const int wr = w >> 1, wc = w & 1;
    const int l15 = lane & 15;

    f32x4 acc[2][4];
    #pragma unroll
    for (int m = 0; m < 2; m++)
        #pragma unroll
        for (int n = 0; n < 4; n++)
            #pragma unroll
            for (int r = 0; r < 4; r++) acc[m][n][r] = 0.f;

    const int srow = lane >> 3;
    const int schk8 = ((lane & 7) ^ (srow & 7)) * 8;
    const bf16* asrc  = Ag   + (size_t)(mt * 64 + srow) * DIM + schk8;
    const bf16* bhsrc = Bh_g + (size_t)(nt * 128 + srow) * DIM + schk8;
    const bf16* blsrc = Bl_g + (size_t)(nt * 128 + srow) * DIM + schk8;

    for (int k0 = 0; k0 < DIM; k0 += 64) {
        __syncthreads();
        #pragma unroll
        for (int ii = 0; ii < 2; ++ii) {
            int i = w * 2 + ii;
            __builtin_amdgcn_global_load_lds(
                GLOBAL_AS(asrc + (size_t)i * 8 * DIM + k0),
                LDS_AS(&Alin[i * 512]), 16, 0, 0);
        }
        #pragma unroll
        for (int jj = 0; jj < 4; ++jj) {
            int j = w * 4 + jj;
            size_t roff = (size_t)j * 8 * DIM + k0;
            __builtin_amdgcn_global_load_lds(GLOBAL_AS(bhsrc + roff),
                                             LDS_AS(&Bhlin[j * 512]), 16, 0, 0);
            __builtin_amdgcn_global_load_lds(GLOBAL_AS(blsrc + roff),
                                             LDS_AS(&Bllin[j * 512]), 16, 0, 0);
        }
        __syncthreads();

        #pragma unroll
        for (int ks = 0; ks < 2; ks++) {
            const int cc = (lane >> 4) + ks * 4;
            bf16x8 fbh[4], fbl[4];
            #pragma unroll
            for (int n = 0; n < 4; n++) {
                int r = wc * 64 + n * 16 + l15;
                int off = r * 64 + ((cc ^ (r & 7)) << 3);
                fbh[n] = *(const bf16x8*)&Bhlin[off];
                fbl[n] = *(const bf16x8*)&Bllin[off];
            }
            #pragma unroll
            for (int m = 0; m < 2; m++) {
                int r = wr * 32 + m * 16 + l15;
                bf16x8 fa = *(const bf16x8*)&Alin[r * 64 + ((cc ^ (r & 7)) << 3)];
                #pragma unroll
                for (int n = 0; n < 4; n++) {
                    acc[m][n] = MFMA16(fa, fbh[n], acc[m][n]);
                    acc[m][n] = MFMA16(fa, fbl[n], acc[m][n]);
                }
            }
        }
    }

    #pragma unroll
    for (int m = 0; m < 2; m++) {
        #pragma unroll
        for (int n = 0; n < 4; n++) {
            const int grow0 = mt * 64 + wr * 32 + m * 16 + (lane >> 4) * 4;
            const int gcol  = nt * 128 + wc * 64 + n * 16 + l15;
            const float bias = bo[gcol];
            #pragma unroll
            for (int r = 0; r < 4; r++)
                f_o[(size_t)(grow0 + r) * DIM + gcol] = acc[m][n][r] + bias;
        }
    }
}

// ---------------------------------------------------------------------------
// Kernel 2: flash attention v9 (verified R18/R20) — async dbuf + T15
// att[2] double-pipeline. 64q/block, 4 blocks/CU, setprio, exp2 raw,
// l on MFMA pipe, named buffers.
// ---------------------------------------------------------------------------
__global__ __launch_bounds__(256) void k_attn(
    const bf16* __restrict__ Q, const bf16* __restrict__ K,
    const bf16* __restrict__ Vt, bf16* __restrict__ O)
{
    __shared__ bf16 Ks0[64 * 64];
    __shared__ bf16 Ks1[64 * 64];
    __shared__ bf16 Vs0[64 * 64];
    __shared__ bf16 Vs1[64 * 64];
    __shared__ bf16 Ps[64 * 64];

    const int fid = blockIdx.x;
    const int swz = (fid & 7) * 128 + (fid >> 3);
    const int qt = swz & 15;
    const int bh = swz >> 4;

    const int t = threadIdx.x;
    const int lane = t & 63;
    const int w = t >> 6;
    const int col = lane & 15;
    const int grp = lane >> 4;
    const int m7 = col & 7;
    const int qrow = w * 16 + col;

    const bf16* qp = Q + ((size_t)bh * TOK + qt * 64 + qrow) * HD + grp * 8;
    bf16x8 qf0 = *(const bf16x8*)qp;
    bf16x8 qf1 = *(const bf16x8*)(qp + 32);

    const int srow = lane >> 3;
    const int schk8 = ((lane & 7) ^ (srow & 7)) * 8;
    const bf16* ksrc = K  + ((size_t)bh * TOK + srow) * HD + schk8;
    const bf16* vsrc = Vt + ((size_t)bh * HD + srow) * TOK + schk8;

    bf16x8 ones;
    #pragma unroll
    for (int j = 0; j < 8; j++) ones[j] = (bf16)1.0f;

    f32x4 zero = {0.f, 0.f, 0.f, 0.f};
    f32x4 lacc = zero;
    f32x4 o_[4];
    #pragma unroll
    for (int dt = 0; dt < 4; dt++) o_[dt] = zero;

    unsigned int* PsU = (unsigned int*)Ps;

    auto stageK = [&](int kt, bf16* kb) {
        #pragma unroll
        for (int ii = 0; ii < 2; ++ii) {
            int i = w * 2 + ii;
            __builtin_amdgcn_global_load_lds(
                GLOBAL_AS(ksrc + (size_t)(kt * 64 + i * 8) * HD),
                LDS_AS(kb + i * 512), 16, 0, 0);
        }
    };
    auto stageV = [&](int kt, bf16* vb) {
        #pragma unroll
        for (int ii = 0; ii < 2; ++ii) {
            int i = w * 2 + ii;
            __builtin_amdgcn_global_load_lds(
                GLOBAL_AS(vsrc + (size_t)(i * 8) * TOK + kt * 64),
                LDS_AS(vb + i * 512), 16, 0, 0);
        }
    };

    auto qkt = [&](const bf16* kb, f32x4* s) {
        #pragma unroll
        for (int ct = 0; ct < 4; ct++) s[ct] = zero;
        __builtin_amdgcn_s_setprio(1);
        #pragma unroll
        for (int ct = 0; ct < 4; ct++) {
            int rbase = (ct * 16 + col) * 64;
            bf16x8 kf0 = *(const bf16x8*)&kb[rbase + ((grp ^ m7) << 3)];
            bf16x8 kf1 = *(const bf16x8*)&kb[rbase + (((grp + 4) ^ m7) << 3)];
            s[ct] = MFMA16(kf0, qf0, s[ct]);
            s[ct] = MFMA16(kf1, qf1, s[ct]);
        }
        __builtin_amdgcn_s_setprio(0);
    };

    auto packpv = [&](const f32x4* s, const bf16* vb) {
        #pragma unroll
        for (int ct = 0; ct < 4; ct++) {
            float p0 = exp2f(s[ct][0]);
            float p1 = exp2f(s[ct][1]);
            float p2 = exp2f(s[ct][2]);
            float p3 = exp2f(s[ct][3]);
            unsigned int a0, a1;
            asm("v_cvt_pk_bf16_f32 %0, %1, %2" : "=v"(a0) : "v"(p0), "v"(p1));
            asm("v_cvt_pk_bf16_f32 %0, %1, %2" : "=v"(a1) : "v"(p2), "v"(p3));
            int cs = (2 * ct + (grp >> 1)) ^ m7;
            u32x2 st = {a0, a1};
            *(u32x2*)&PsU[qrow * 32 + cs * 4 + (grp & 1) * 2] = st;
        }
        __builtin_amdgcn_s_setprio(1);
        #pragma unroll
        for (int tt = 0; tt < 2; tt++) {
            const int coff = ((4 * tt + grp) ^ m7) << 3;
            bf16x8 pf = *(const bf16x8*)&Ps[qrow * 64 + coff];
            lacc = MFMA16(ones, pf, lacc);
            #pragma unroll
            for (int dt = 0; dt < 4; dt++) {
                bf16x8 vf = *(const bf16x8*)&vb[(dt * 16 + col) * 64 + coff];
                o_[dt] = MFMA16(vf, pf, o_[dt]);
            }
        }
        __builtin_amdgcn_s_setprio(0);
    };

    f32x4 sa[4], sprev[4];

    stageK(0, Ks0);
    stageV(0, Vs0);
    #pragma unroll 1
    for (int kk = 0; kk < 8; kk++) {
        __syncthreads();
        stageK(2 * kk + 1, Ks1);
        if (kk > 0) stageV(2 * kk, Vs0);
        qkt(Ks0, sa);
        if (kk > 0) packpv(sprev, Vs1);
        __syncthreads();
        if (kk < 7) stageK(2 * kk + 2, Ks0);
        stageV(2 * kk + 1, Vs1);
        qkt(Ks1, sprev);
        packpv(sa, Vs0);
    }
    __syncthreads();
    packpv(sprev, Vs1);

    const float inv = 1.0f / lacc[0];

    const int b = bh >> 4, h = bh & 15;
    const int ntok = qt * 64 + qrow;
    #pragma unroll
    for (int dt = 0; dt < 4; dt++) {
        bf16x4 pk4;
        #pragma unroll
        for (int r = 0; r < 4; r++) pk4[r] = (bf16)(o_[dt][r] * inv);
        *(bf16x4*)&O[((size_t)b * TOK + ntok) * DIM + h * HD + dt * 16 + grp * 4] = pk4;
    }
}

// ---------------------------------------------------------------------------
extern "C" void kernel_launch(void* const* d_in, const int* in_sizes, int n_in,
                              void* d_out, int out_size, void* d_ws, size_t ws_size,
                              hipStream_t stream)
{
    const float* x    = (const float*)d_in[0];
    const float* cosT = (const float*)d_in[1];
    const float* sinT = (const float*)d_in[2];
    const float* Wq   = (const float*)d_in[3];
    const float* Wk   = (const float*)d_in[4];
    const float* Wv   = (const float*)d_in[5];
    const float* Wo   = (const float*)d_in[6];
    const float* bo   = (const float*)d_in[7];
    float* out = (float*)d_out;

    // ws layout (bf16 elems): xh[0,4M) qw[4M,8M) kw[8M,12M) vw[12M,16M)
    // wsp[16M,21M) = 42MB. ow aliases xh (xh dead after QKV GEMM).
    bf16* xh  = (bf16*)d_ws;
    bf16* qw  = xh + 4 * (size_t)MELEM;
    bf16* kw  = qw + 4 * (size_t)MELEM;
    bf16* vw  = kw + 4 * (size_t)MELEM;
    bf16* wsp = vw + 4 * (size_t)MELEM;
    bf16* ow  = xh;

    k_prep<<<dim3(3584), dim3(256), 0, stream>>>(x, Wq, Wk, Wv, xh, wsp);
    k_gemmQKV<<<dim3(640), dim3(512), 0, stream>>>(
        xh, wsp, Wo, wsp, cosT, sinT, qw, kw, vw);
    k_attn<<<dim3(1024), dim3(256), 0, stream>>>(qw, kw, vw, ow);
    k_gemmO<<<dim3(512), dim3(256), 0, stream>>>(ow, wsp, bo, out);
}